// Round 1
// baseline (1104.178 us; speedup 1.0000x reference)
//
#include <hip/hip_runtime.h>
#include <hip/hip_bf16.h>

// Problem constants (fixed by the reference):
#define DID 512              // in_dim  (GEMM K)
#define NV  512              // n_vars  (tokens per batch image)
#define NB  64               // batch
#define OD  720              // out_dim (GEMM M, valid)
#define OPAD 768             // out_dim padded to a multiple of 128
#define NE  8                // experts
#define NTOK (NB * NV)       // 32768 tokens total

typedef short  bf16x8 __attribute__((ext_vector_type(8)));   // 8 bf16 (4 VGPRs)
typedef float  f32x4  __attribute__((ext_vector_type(4)));   // MFMA accumulator

static __device__ __forceinline__ ushort f2bf(float f) {
  // round-to-nearest-even fp32 -> bf16 (bit trick; data has no NaNs)
  unsigned u = __float_as_uint(f);
  unsigned r = (u + 0x7fffu + ((u >> 16) & 1u)) >> 16;
  return (ushort)r;
}

static __device__ __forceinline__ void async16(const ushort* g, ushort* l) {
  // direct global->LDS DMA, 16B per lane; LDS dest = wave-uniform base + lane*16
  __builtin_amdgcn_global_load_lds((__attribute__((address_space(1))) void*)(g),
                                   (__attribute__((address_space(3))) void*)(l),
                                   16, 0, 0);
}

// ---------------------------------------------------------------------------
// Kernel 1: x [B][D][V] fp32  ->  XT [B][V][D] bf16 (token-major rows)
// ---------------------------------------------------------------------------
__global__ __launch_bounds__(256) void k_transpose(const float* __restrict__ x,
                                                   ushort* __restrict__ xt) {
  __shared__ float s[32][33];                   // +1 pad: conflict-free transpose
  const int b  = blockIdx.z;
  const int v0 = blockIdx.x * 32;
  const int d0 = blockIdx.y * 32;
  const int tx = threadIdx.x & 31;              // along v on load, along d on store
  const int ty = threadIdx.x >> 5;              // 8 rows, x4 iterations

  const float* xp = x + ((size_t)b * DID + d0 + ty) * NV + v0 + tx;
#pragma unroll
  for (int i = 0; i < 4; ++i)
    s[ty + i * 8][tx] = xp[(size_t)i * 8 * NV];
  __syncthreads();
#pragma unroll
  for (int i = 0; i < 4; ++i) {
    int vl = ty + i * 8;
    xt[((size_t)b * NV + v0 + vl) * DID + d0 + tx] = f2bf(s[tx][vl]);
  }
}

// ---------------------------------------------------------------------------
// Kernel 2: We [E][720][512] fp32 -> WB [E][768][512] bf16, pad rows = 0
// ---------------------------------------------------------------------------
__global__ __launch_bounds__(256) void k_wbconv(const float* __restrict__ We,
                                                ushort* __restrict__ wb) {
  const int e = blockIdx.y;
  const int i = blockIdx.x * 256 + threadIdx.x;   // over OPAD*DID = 393216
  const int o = i >> 9;
  ushort val = 0;
  if (o < OD) val = f2bf(We[(size_t)e * OD * DID + i]);
  wb[(size_t)e * OPAD * DID + i] = val;
}

// ---------------------------------------------------------------------------
// Kernel 3: gating. Per token: logits = x_tok . Wg[e], softmax, top-2,
// append (token, coef) into per-expert lists (block-aggregated atomics).
// ---------------------------------------------------------------------------
__global__ __launch_bounds__(256) void k_gate(const float* __restrict__ x,
                                              const float* __restrict__ Wg,
                                              int* __restrict__ tlist,
                                              float* __restrict__ clist,
                                              int* __restrict__ cnt) {
  __shared__ float wg[NE * DID];                 // 16 KB
  __shared__ int cnt8[NE];
  __shared__ int base8[NE];
  const int tid = threadIdx.x;
  for (int i = tid; i < NE * DID; i += 256) wg[i] = Wg[i];
  if (tid < NE) cnt8[tid] = 0;
  __syncthreads();

  const int b = blockIdx.y;
  const int v = blockIdx.x * 256 + tid;
  const float* xp = x + (size_t)b * DID * NV + v;

  float acc[NE];
#pragma unroll
  for (int e = 0; e < NE; ++e) acc[e] = 0.f;

  for (int d = 0; d < DID; d += 4) {
    float x0 = xp[(size_t)(d + 0) * NV];
    float x1 = xp[(size_t)(d + 1) * NV];
    float x2 = xp[(size_t)(d + 2) * NV];
    float x3 = xp[(size_t)(d + 3) * NV];
#pragma unroll
    for (int e = 0; e < NE; ++e) {
      float4 w4 = *(const float4*)&wg[e * DID + d];
      acc[e] += x0 * w4.x + x1 * w4.y + x2 * w4.z + x3 * w4.w;
    }
  }

  // softmax over 8
  float mx = acc[0];
#pragma unroll
  for (int e = 1; e < NE; ++e) mx = fmaxf(mx, acc[e]);
  float sum = 0.f;
#pragma unroll
  for (int e = 0; e < NE; ++e) { acc[e] = __expf(acc[e] - mx); sum += acc[e]; }
  const float inv = 1.f / sum;

  // top-2 (ties -> lower index, matching lax.top_k)
  int i1 = 0; float g1 = acc[0];
#pragma unroll
  for (int e = 1; e < NE; ++e) if (acc[e] > g1) { g1 = acc[e]; i1 = e; }
  int i2 = -1; float g2 = -1.f;
#pragma unroll
  for (int e = 0; e < NE; ++e) if (e != i1 && acc[e] > g2) { g2 = acc[e]; i2 = e; }
  g1 *= inv; g2 *= inv;

  const int p1 = atomicAdd(&cnt8[i1], 1);
  const int p2 = atomicAdd(&cnt8[i2], 1);
  __syncthreads();
  if (tid < NE) base8[tid] = atomicAdd(&cnt[tid], cnt8[tid]);
  __syncthreads();

  const int t = b * NV + v;
  const int q1 = i1 * NTOK + base8[i1] + p1;
  const int q2 = i2 * NTOK + base8[i2] + p2;
  tlist[q1] = t; clist[q1] = g1;
  tlist[q2] = t; clist[q2] = g2;
}

// ---------------------------------------------------------------------------
// Kernel 4: gathered per-expert GEMM (m97 structure).
// Tile: 128 o x 128 tokens, BK=32, 256 thr = 4 waves, wave tile 64x64
// (4x4 frags of v_mfma_f32_16x16x32_bf16). B rows gathered via token list.
// Epilogue: atomicAdd(out[b][o][v], coef * (acc + be[e][o])).
// ---------------------------------------------------------------------------
__global__ __launch_bounds__(256) void k_gemm(const ushort* __restrict__ xt,
                                              const ushort* __restrict__ wb,
                                              const float* __restrict__ be,
                                              const int* __restrict__ tlist,
                                              const float* __restrict__ clist,
                                              const int* __restrict__ cnt,
                                              float* __restrict__ out) {
  const int e  = blockIdx.z;
  const int t0 = blockIdx.x * 128;
  if (t0 >= cnt[e]) return;                      // inactive tile (uniform branch)
  const int o0 = blockIdx.y * 128;

  __shared__ __align__(16) ushort As[128 * 32];  // [o_local][k_local], 64B rows
  __shared__ __align__(16) ushort Bs[128 * 32];  // [tok_local][k_local]

  const int tid  = threadIdx.x;
  const int lane = tid & 63;
  const int w    = tid >> 6;

  // staging: 16B unit f = w*128 + c*64 + lane; row = f>>2, chunk = f&3
  const int f0 = w * 128 + lane;
  const int f1 = f0 + 64;
  const int r0 = f0 >> 2, ch0 = f0 & 3;
  const int r1 = f1 >> 2, ch1 = f1 & 3;

  const ushort* ga0 = wb + ((size_t)e * OPAD + o0 + r0) * DID + ch0 * 8;
  const ushort* ga1 = wb + ((size_t)e * OPAD + o0 + r1) * DID + ch1 * 8;
  const int ta = tlist[e * NTOK + t0 + r0];      // gather source rows (4 lanes share)
  const int tb = tlist[e * NTOK + t0 + r1];
  const ushort* gb0 = xt + (size_t)ta * DID + ch0 * 8;
  const ushort* gb1 = xt + (size_t)tb * DID + ch1 * 8;

  ushort* la0 = As + w * 1024;                   // wave-uniform LDS bases
  ushort* la1 = As + w * 1024 + 512;
  ushort* lb0 = Bs + w * 1024;
  ushort* lb1 = Bs + w * 1024 + 512;

  const int m    = lane & 15;
  const int quad = lane >> 4;
  const int wo   = (w >> 1) * 64;                // wave offset in o
  const int wt   = (w & 1) * 64;                 // wave offset in tokens

  f32x4 acc[4][4];
#pragma unroll
  for (int i = 0; i < 4; ++i)
#pragma unroll
    for (int j = 0; j < 4; ++j) acc[i][j] = (f32x4){0.f, 0.f, 0.f, 0.f};

  for (int k0 = 0; k0 < DID; k0 += 32) {
    __syncthreads();                             // prior frag reads done before overwrite
    async16(ga0 + k0, la0);
    async16(ga1 + k0, la1);
    async16(gb0 + k0, lb0);
    async16(gb1 + k0, lb1);
    __syncthreads();                             // drains vmcnt -> LDS tiles ready

    bf16x8 af[4], bfr[4];
#pragma unroll
    for (int i = 0; i < 4; ++i)
      af[i] = *(const bf16x8*)(As + (wo + i * 16 + m) * 32 + quad * 8);
#pragma unroll
    for (int j = 0; j < 4; ++j)
      bfr[j] = *(const bf16x8*)(Bs + (wt + j * 16 + m) * 32 + quad * 8);
#pragma unroll
    for (int i = 0; i < 4; ++i)
#pragma unroll
      for (int j = 0; j < 4; ++j)
        acc[i][j] = __builtin_amdgcn_mfma_f32_16x16x32_bf16(af[i], bfr[j],
                                                            acc[i][j], 0, 0, 0);
  }

  // Epilogue: C/D layout col=lane&15 (token), row=quad*4+reg (o).
#pragma unroll
  for (int j = 0; j < 4; ++j) {
    const int colL = wt + j * 16 + m;
    const int tcol = tlist[e * NTOK + t0 + colL];
    const float cc = clist[e * NTOK + t0 + colL];
    if (cc != 0.f) {                             // padding slots contribute nothing
      const int bb = tcol >> 9;                  // token = b*512 + v
      const int vv = tcol & 511;
      float* op = out + (size_t)bb * OD * NV + vv;
#pragma unroll
      for (int i = 0; i < 4; ++i) {
#pragma unroll
        for (int r = 0; r < 4; ++r) {
          const int o = o0 + wo + i * 16 + quad * 4 + r;
          if (o < OD)
            atomicAdd(op + (size_t)o * NV, cc * (acc[i][j][r] + be[e * OD + o]));
        }
      }
    }
  }
}

// ---------------------------------------------------------------------------
// Workspace layout (bytes):
//   XT    @ 0          : 64*512*512*2  = 33,554,432
//   WB    @ 33,554,432 :  8*768*512*2  =  6,291,456
//   tlist @ 39,845,888 :  8*32768*4    =  1,048,576
//   clist @ 40,894,464 :  8*32768*4    =  1,048,576
//   cnt   @ 41,943,040 :  8*4          =         32
// total ~40 MiB
// ---------------------------------------------------------------------------
extern "C" void kernel_launch(void* const* d_in, const int* in_sizes, int n_in,
                              void* d_out, int out_size, void* d_ws, size_t ws_size,
                              hipStream_t stream) {
  const float* x  = (const float*)d_in[0];   // [64][512][512]
  const float* Wg = (const float*)d_in[1];   // [8][512]
  const float* We = (const float*)d_in[2];   // [8][720][512]
  const float* be = (const float*)d_in[3];   // [8][720]
  // d_in[4] = top_k, always 2 for this problem.
  float* out = (float*)d_out;                // [64][720][512]

  char* ws = (char*)d_ws;
  ushort* xt    = (ushort*)(ws);
  ushort* wb    = (ushort*)(ws + 33554432);
  int*    tlist = (int*)  (ws + 39845888);
  float*  clist = (float*)(ws + 40894464);
  int*    cnt   = (int*)  (ws + 41943040);

  // zero routing lists + counters (padding slots must read as coef 0), zero out
  (void)hipMemsetAsync(tlist, 0, 2097184, stream);
  (void)hipMemsetAsync(d_out, 0, (size_t)out_size * sizeof(float), stream);

  k_transpose<<<dim3(NV / 32, DID / 32, NB), 256, 0, stream>>>(x, xt);
  k_wbconv<<<dim3(OPAD * DID / 256, NE), 256, 0, stream>>>(We, wb);
  k_gate<<<dim3(NV / 256, NB), 256, 0, stream>>>(x, Wg, tlist, clist, cnt);
  // worst-case grid; tiles past cnt[e] exit immediately
  k_gemm<<<dim3(NTOK / 128, OPAD / 128, NE), 256, 0, stream>>>(
      xt, wb, be, tlist, clist, cnt, out);
}

// Round 2
// 340.242 us; speedup vs baseline: 3.2453x; 3.2453x over previous
//
#include <hip/hip_runtime.h>
#include <hip/hip_bf16.h>

#define DID 512              // in_dim (K)
#define NV  512              // n_vars (tokens per batch)
#define NB  64               // batch
#define OD  720              // out_dim
#define OPAD 768             // out_dim padded to 128-multiple
#define NE  8                // experts
#define NTOK (NB * NV)       // 32768 tokens
#define MAXTILE 512          // >= 28 + 32768/128 = 284 worst case

typedef short  bf16x8 __attribute__((ext_vector_type(8)));
typedef float  f32x4  __attribute__((ext_vector_type(4)));

// ---- workspace offsets (bytes) ----
#define XT_OFF    0u          // bf16 [B][V][D]          33,554,432
#define WB_OFF    33554432u   // bf16 [E][OPAD][D]        6,291,456
#define PID_OFF   39845888u   // int  [NTOK] pair id        131,072
#define C1D_OFF   39976960u   // f32  [NTOK] coef lo-e      131,072
#define C2D_OFF   40108032u   // f32  [NTOK] coef hi-e      131,072
#define TL_OFF    40239104u   // int  [NTOK] bucketed tok   131,072
#define CL1_OFF   40370176u   // f32  [NTOK]                131,072
#define CL2_OFF   40501248u   // f32  [NTOK]                131,072
#define BCNT_OFF  40632320u   // int[64]
#define BFILL_OFF 40632576u   // int[64]
#define BOFF_OFF  40632832u   // int[64]
#define TPID_OFF  40633088u   // int[MAXTILE]
#define TT0_OFF   40635136u   // int[MAXTILE]
#define TEND_OFF  40637184u   // int[MAXTILE]
#define NT_OFF    40639232u   // int[1]
#define SCR_OFF   40639488u   // bf16 [NTOK][OD]         47,185,920
#define SCR_END   87825408u

static __device__ __forceinline__ ushort f2bf(float f) {
  unsigned u = __float_as_uint(f);
  unsigned r = (u + 0x7fffu + ((u >> 16) & 1u)) >> 16;   // RNE
  return (ushort)r;
}
static __device__ __forceinline__ float bf2f(ushort u) {
  return __uint_as_float(((unsigned)u) << 16);
}
static __device__ __forceinline__ void async16(const ushort* g, ushort* l) {
  __builtin_amdgcn_global_load_lds((__attribute__((address_space(1))) void*)(g),
                                   (__attribute__((address_space(3))) void*)(l),
                                   16, 0, 0);
}
// chunk swizzle: spreads 64B-stride rows across 8 bank-sets (2-way = free)
static __device__ __forceinline__ int swz(int r) { return (r & 3) ^ ((r >> 2) & 1); }

// ---------------------------------------------------------------------------
// x [B][D][V] fp32 -> XT [B][V][D] bf16
// ---------------------------------------------------------------------------
__global__ __launch_bounds__(256) void k_transpose(const float* __restrict__ x,
                                                   ushort* __restrict__ xt) {
  __shared__ float s[32][33];
  const int b  = blockIdx.z;
  const int v0 = blockIdx.x * 32;
  const int d0 = blockIdx.y * 32;
  const int tx = threadIdx.x & 31;
  const int ty = threadIdx.x >> 5;
  const float* xp = x + ((size_t)b * DID + d0 + ty) * NV + v0 + tx;
#pragma unroll
  for (int i = 0; i < 4; ++i) s[ty + i * 8][tx] = xp[(size_t)i * 8 * NV];
  __syncthreads();
#pragma unroll
  for (int i = 0; i < 4; ++i) {
    int vl = ty + i * 8;
    xt[((size_t)b * NV + v0 + vl) * DID + d0 + tx] = f2bf(s[tx][vl]);
  }
}

// ---------------------------------------------------------------------------
// We [E][720][512] fp32 -> WB [E][768][512] bf16 (pad rows zero)
// ---------------------------------------------------------------------------
__global__ __launch_bounds__(256) void k_wbconv(const float* __restrict__ We,
                                                ushort* __restrict__ wb) {
  const int e = blockIdx.y;
  const int i = blockIdx.x * 256 + threadIdx.x;
  const int o = i >> 9;
  ushort val = 0;
  if (o < OD) val = f2bf(We[(size_t)e * OD * DID + i]);
  wb[(size_t)e * OPAD * DID + i] = val;
}

// ---------------------------------------------------------------------------
// Gating (fp32 exact): per-token logits, softmax, top-2 -> dense
// (pairid, c_lo, c_hi) + per-pair-bucket counts.
// ---------------------------------------------------------------------------
__global__ __launch_bounds__(256) void k_gate(const float* __restrict__ x,
                                              const float* __restrict__ Wg,
                                              int* __restrict__ pairid,
                                              float* __restrict__ c1d,
                                              float* __restrict__ c2d,
                                              int* __restrict__ bcnt) {
  __shared__ float wg[NE * DID];
  __shared__ int cnt64[64];
  const int tid = threadIdx.x;
  for (int i = tid; i < NE * DID; i += 256) wg[i] = Wg[i];
  if (tid < 64) cnt64[tid] = 0;
  __syncthreads();

  const int b = blockIdx.y;
  const int v = blockIdx.x * 256 + tid;
  const float* xp = x + (size_t)b * DID * NV + v;

  float acc[NE];
#pragma unroll
  for (int e = 0; e < NE; ++e) acc[e] = 0.f;
  for (int d = 0; d < DID; d += 4) {
    float x0 = xp[(size_t)(d + 0) * NV];
    float x1 = xp[(size_t)(d + 1) * NV];
    float x2 = xp[(size_t)(d + 2) * NV];
    float x3 = xp[(size_t)(d + 3) * NV];
#pragma unroll
    for (int e = 0; e < NE; ++e) {
      float4 w4 = *(const float4*)&wg[e * DID + d];
      acc[e] += x0 * w4.x + x1 * w4.y + x2 * w4.z + x3 * w4.w;
    }
  }
  float mx = acc[0];
#pragma unroll
  for (int e = 1; e < NE; ++e) mx = fmaxf(mx, acc[e]);
  float sum = 0.f;
#pragma unroll
  for (int e = 0; e < NE; ++e) { acc[e] = __expf(acc[e] - mx); sum += acc[e]; }
  const float inv = 1.f / sum;

  int i1 = 0; float g1 = acc[0];
#pragma unroll
  for (int e = 1; e < NE; ++e) if (acc[e] > g1) { g1 = acc[e]; i1 = e; }
  int i2 = -1; float g2 = -1.f;
#pragma unroll
  for (int e = 0; e < NE; ++e) if (e != i1 && acc[e] > g2) { g2 = acc[e]; i2 = e; }
  g1 *= inv; g2 *= inv;

  int ea, eb; float ca, cb;
  if (i1 < i2) { ea = i1; eb = i2; ca = g1; cb = g2; }
  else         { ea = i2; eb = i1; ca = g2; cb = g1; }
  const int pid = ea * 8 + eb;
  const int t = b * NV + v;
  pairid[t] = pid; c1d[t] = ca; c2d[t] = cb;
  atomicAdd(&cnt64[pid], 1);
  __syncthreads();
  if (tid < 64 && cnt64[tid]) atomicAdd(&bcnt[tid], cnt64[tid]);
}

// ---------------------------------------------------------------------------
// Serial prefix over 64 buckets + tile table build (trivial size)
// ---------------------------------------------------------------------------
__global__ void k_prefix(const int* __restrict__ bcnt, int* __restrict__ boffs,
                         int* __restrict__ tpid, int* __restrict__ tt0,
                         int* __restrict__ tend, int* __restrict__ ntp) {
  if (threadIdx.x != 0) return;
  int off = 0, nt = 0;
  for (int p = 0; p < 64; ++p) {
    boffs[p] = off;
    const int c = bcnt[p];
    const int end = off + c;
    for (int i = 0; i * 128 < c; ++i) {
      tpid[nt] = p; tt0[nt] = off + i * 128; tend[nt] = end; ++nt;
    }
    off = end;
  }
  ntp[0] = nt;
}

// ---------------------------------------------------------------------------
// Scatter tokens into packed per-bucket lists
// ---------------------------------------------------------------------------
__global__ __launch_bounds__(256) void k_scatter(const int* __restrict__ pairid,
                                                 const float* __restrict__ c1d,
                                                 const float* __restrict__ c2d,
                                                 const int* __restrict__ boffs,
                                                 int* __restrict__ bfill,
                                                 int* __restrict__ tlist,
                                                 float* __restrict__ cl1,
                                                 float* __restrict__ cl2) {
  __shared__ int cnt64[64], base64[64];
  const int tid = threadIdx.x;
  if (tid < 64) cnt64[tid] = 0;
  __syncthreads();
  const int t = blockIdx.x * 256 + tid;
  const int pid = pairid[t];
  const int p = atomicAdd(&cnt64[pid], 1);
  __syncthreads();
  if (tid < 64) base64[tid] = cnt64[tid] ? atomicAdd(&bfill[tid], cnt64[tid]) : 0;
  __syncthreads();
  const int slot = boffs[pid] + base64[pid] + p;
  tlist[slot] = t; cl1[slot] = c1d[t]; cl2[slot] = c2d[t];
}

// ---------------------------------------------------------------------------
// Pair-bucket GEMM: 128 tokens x 128 o, both experts sequentially into one
// accumulator (fold trick), double-buffered LDS, swizzled chunks, no atomics.
// mode 0: write bf16 scratch [tok][OD]; mode 1: direct strided fp32 stores.
// ---------------------------------------------------------------------------
__global__ __launch_bounds__(256, 2) void k_gemm(
    const ushort* __restrict__ xt, const ushort* __restrict__ wb,
    const float* __restrict__ be, const int* __restrict__ tlist,
    const float* __restrict__ cl1, const float* __restrict__ cl2,
    const int* __restrict__ tpid, const int* __restrict__ tt0,
    const int* __restrict__ tendarr, const int* __restrict__ ntp,
    ushort* __restrict__ scratch, float* __restrict__ out, int mode) {
  const int tile = blockIdx.x;
  if (tile >= ntp[0]) return;
  const int pid  = tpid[tile];
  const int t0   = tt0[tile];
  const int tend = tendarr[tile];
  const int e1 = pid >> 3, e2 = pid & 7;
  const int o0 = blockIdx.y * 128;

  __shared__ __align__(16) ushort As[2][4096];   // 128 rows x 32 (8KB each)
  __shared__ __align__(16) ushort Bs[2][4096];

  const int tid  = threadIdx.x;
  const int lane = tid & 63;
  const int w    = tid >> 6;

  // staging lane->slot: f covers (row, phys-chunk); source chunk is swizzled
  const int f0 = w * 128 + lane, f1 = f0 + 64;
  const int r0 = f0 >> 2, p0 = f0 & 3, q0 = p0 ^ swz(r0);
  const int r1 = f1 >> 2, p1 = f1 & 3, q1 = p1 ^ swz(r1);

  const int aoff0 = (o0 + r0) * DID + q0 * 8;
  const int aoff1 = (o0 + r1) * DID + q1 * 8;
  const int sl0 = t0 + r0, sl1 = t0 + r1;
  const int tok0 = (sl0 < tend) ? tlist[sl0] : 0;
  const int tok1 = (sl1 < tend) ? tlist[sl1] : 0;
  const int boff0 = tok0 * DID + q0 * 8;
  const int boff1 = tok1 * DID + q1 * 8;
  const int dA0 = w * 1024, dA1 = w * 1024 + 512;   // ushort offsets (wave-uniform)

  const int m    = lane & 15;
  const int quad = lane >> 4;
  const int wo   = (w >> 1) * 64;
  const int wt   = (w & 1) * 64;

  f32x4 acc[4][4];
#pragma unroll
  for (int i = 0; i < 4; ++i)
#pragma unroll
    for (int j = 0; j < 4; ++j) acc[i][j] = (f32x4){0.f, 0.f, 0.f, 0.f};

  // prologue: stage kk=0 (expert e1, k0=0) into buffer 0
  {
    const ushort* wA = wb + (size_t)e1 * OPAD * DID;
    async16(wA + aoff0, &As[0][dA0]);
    async16(wA + aoff1, &As[0][dA1]);
    async16(xt + boff0, &Bs[0][dA0]);
    async16(xt + boff1, &Bs[0][dA1]);
  }

  for (int kk = 0; kk < 32; ++kk) {
    __syncthreads();   // waits vmcnt (stage kk) + lgkm (frag reads of kk-1)

    if (kk == 16) {
      // fold expert-1: acc = (acc + be1[o]) * (c1/c2) per column
      float ratio[4];
#pragma unroll
      for (int j = 0; j < 4; ++j) {
        const int sl = t0 + wt + j * 16 + m;
        const bool g = sl < tend;
        const float cc1 = g ? cl1[sl] : 0.f;
        const float cc2 = g ? cl2[sl] : 1.f;
        ratio[j] = cc1 / cc2;
      }
      const float* be1p = be + e1 * OD;
#pragma unroll
      for (int i = 0; i < 4; ++i) {
        const int ob = o0 + wo + i * 16 + quad * 4;
        float b0 = 0, b1 = 0, b2 = 0, b3 = 0;
        if (ob < OD) { b0 = be1p[ob]; b1 = be1p[ob + 1]; b2 = be1p[ob + 2]; b3 = be1p[ob + 3]; }
#pragma unroll
        for (int j = 0; j < 4; ++j) {
          acc[i][j][0] = (acc[i][j][0] + b0) * ratio[j];
          acc[i][j][1] = (acc[i][j][1] + b1) * ratio[j];
          acc[i][j][2] = (acc[i][j][2] + b2) * ratio[j];
          acc[i][j][3] = (acc[i][j][3] + b3) * ratio[j];
        }
      }
    }

    // prefetch next tile into the other buffer (overlaps this tile's MFMA)
    const int nk = kk + 1;
    if (nk < 32) {
      const int nb = nk & 1;
      const int eA = (nk < 16) ? e1 : e2;
      const int k0 = (nk & 15) * 32;
      const ushort* wA = wb + (size_t)eA * OPAD * DID + k0;
      async16(wA + aoff0, &As[nb][dA0]);
      async16(wA + aoff1, &As[nb][dA1]);
      async16(xt + boff0 + k0, &Bs[nb][dA0]);
      async16(xt + boff1 + k0, &Bs[nb][dA1]);
    }

    const int cb = kk & 1;
    bf16x8 af[4], bfr[4];
#pragma unroll
    for (int i = 0; i < 4; ++i) {
      const int R = wo + i * 16 + m;
      af[i] = *(const bf16x8*)(&As[cb][R * 32 + ((quad ^ swz(R)) << 3)]);
    }
#pragma unroll
    for (int j = 0; j < 4; ++j) {
      const int R = wt + j * 16 + m;
      bfr[j] = *(const bf16x8*)(&Bs[cb][R * 32 + ((quad ^ swz(R)) << 3)]);
    }
#pragma unroll
    for (int i = 0; i < 4; ++i)
#pragma unroll
      for (int j = 0; j < 4; ++j)
        acc[i][j] = __builtin_amdgcn_mfma_f32_16x16x32_bf16(af[i], bfr[j],
                                                            acc[i][j], 0, 0, 0);
  }

  // epilogue: val = c2 * (acc + be2[o]); write exactly once, no atomics
  float c2v[4]; int tokv[4]; bool gv[4];
#pragma unroll
  for (int j = 0; j < 4; ++j) {
    const int sl = t0 + wt + j * 16 + m;
    gv[j] = sl < tend;
    c2v[j]  = gv[j] ? cl2[sl] : 0.f;
    tokv[j] = gv[j] ? tlist[sl] : 0;
  }
  const float* be2p = be + e2 * OD;
#pragma unroll
  for (int i = 0; i < 4; ++i) {
    const int ob = o0 + wo + i * 16 + quad * 4;
    if (ob < OD) {
      const float b0 = be2p[ob], b1 = be2p[ob + 1], b2 = be2p[ob + 2], b3 = be2p[ob + 3];
#pragma unroll
      for (int j = 0; j < 4; ++j) {
        if (gv[j]) {
          const float v0 = c2v[j] * (acc[i][j][0] + b0);
          const float v1 = c2v[j] * (acc[i][j][1] + b1);
          const float v2 = c2v[j] * (acc[i][j][2] + b2);
          const float v3 = c2v[j] * (acc[i][j][3] + b3);
          if (mode == 0) {
            ushort4 pk = make_ushort4(f2bf(v0), f2bf(v1), f2bf(v2), f2bf(v3));
            *(ushort4*)(scratch + (size_t)tokv[j] * OD + ob) = pk;
          } else {
            const int bb = tokv[j] >> 9, vv = tokv[j] & 511;
            float* op = out + ((size_t)bb * OD + ob) * NV + vv;
            op[0] = v0; op[(size_t)NV] = v1; op[2 * (size_t)NV] = v2; op[3 * (size_t)NV] = v3;
          }
        }
      }
    }
  }
}

// ---------------------------------------------------------------------------
// scratch bf16 [NTOK][OD] -> out fp32 [B][OD][V] (LDS transpose, coalesced)
// ---------------------------------------------------------------------------
__global__ __launch_bounds__(256) void k_combine(const ushort* __restrict__ scratch,
                                                 float* __restrict__ out) {
  __shared__ ushort s[64][68];   // 8B-aligned rows
  const int v0 = blockIdx.x * 64;
  const int o0 = blockIdx.y * 64;
  const int b  = blockIdx.z;
  const int tid = threadIdx.x;
#pragma unroll
  for (int it = 0; it < 2; ++it) {
    const int c = it * 256 + tid;            // 512 chunks of 8 o
    const int row = c >> 3, cg = c & 7;
    const int o = o0 + cg * 8;
    if (o + 8 <= OD) {
      const ushort* src = scratch + ((size_t)(b * NV + v0 + row)) * OD + o;
      ushort4 ua = *(const ushort4*)(src);
      ushort4 ub = *(const ushort4*)(src + 4);
      *(ushort4*)&s[row][cg * 8] = ua;
      *(ushort4*)&s[row][cg * 8 + 4] = ub;
    }
  }
  __syncthreads();
  const int vv = tid & 63;
  const int og = tid >> 6;                   // 4 groups of 8 o-pairs
#pragma unroll
  for (int oi = 0; oi < 8; ++oi) {
    const int ol = (og * 8 + oi) * 2;
    const int o = o0 + ol;
    if (o < OD) {
      ushort2 u = *(const ushort2*)&s[vv][ol];
      float* op = out + ((size_t)b * OD + o) * NV + v0 + vv;
      op[0]  = bf2f(u.x);
      op[NV] = bf2f(u.y);
    }
  }
}

// ---------------------------------------------------------------------------
extern "C" void kernel_launch(void* const* d_in, const int* in_sizes, int n_in,
                              void* d_out, int out_size, void* d_ws, size_t ws_size,
                              hipStream_t stream) {
  const float* x  = (const float*)d_in[0];
  const float* Wg = (const float*)d_in[1];
  const float* We = (const float*)d_in[2];
  const float* be = (const float*)d_in[3];
  float* out = (float*)d_out;

  char* ws = (char*)d_ws;
  ushort* xt     = (ushort*)(ws + XT_OFF);
  ushort* wb     = (ushort*)(ws + WB_OFF);
  int*    pairid = (int*)   (ws + PID_OFF);
  float*  c1d    = (float*) (ws + C1D_OFF);
  float*  c2d    = (float*) (ws + C2D_OFF);
  int*    tlist  = (int*)   (ws + TL_OFF);
  float*  cl1    = (float*) (ws + CL1_OFF);
  float*  cl2    = (float*) (ws + CL2_OFF);
  int*    bcnt   = (int*)   (ws + BCNT_OFF);
  int*    bfill  = (int*)   (ws + BFILL_OFF);
  int*    boffs  = (int*)   (ws + BOFF_OFF);
  int*    tpid   = (int*)   (ws + TPID_OFF);
  int*    tt0    = (int*)   (ws + TT0_OFF);
  int*    tend   = (int*)   (ws + TEND_OFF);
  int*    ntp    = (int*)   (ws + NT_OFF);
  ushort* scratch= (ushort*)(ws + SCR_OFF);

  const int mode = (ws_size >= (size_t)SCR_END) ? 0 : 1;  // constant across calls

  (void)hipMemsetAsync(bcnt, 0, 512, stream);             // bcnt + bfill

  k_transpose<<<dim3(NV / 32, DID / 32, NB), 256, 0, stream>>>(x, xt);
  k_wbconv<<<dim3(OPAD * DID / 256, NE), 256, 0, stream>>>(We, wb);
  k_gate<<<dim3(NV / 256, NB), 256, 0, stream>>>(x, Wg, pairid, c1d, c2d, bcnt);
  k_prefix<<<1, 64, 0, stream>>>(bcnt, boffs, tpid, tt0, tend, ntp);
  k_scatter<<<NTOK / 256, 256, 0, stream>>>(pairid, c1d, c2d, boffs, bfill,
                                            tlist, cl1, cl2);
  k_gemm<<<dim3(320, OPAD / 128), 256, 0, stream>>>(xt, wb, be, tlist, cl1, cl2,
                                                    tpid, tt0, tend, ntp,
                                                    scratch, out, mode);
  if (mode == 0)
    k_combine<<<dim3(NV / 64, (OD + 63) / 64, NB), 256, 0, stream>>>(scratch, out);
}